// Round 2
// baseline (254.411 us; speedup 1.0000x reference)
//
#include <hip/hip_runtime.h>
#include <hip/hip_bf16.h>

#define N_NODES 100000
#define N_EDGES 1600000
#define D 128
#define N_TILES 6250             // N_NODES/16
#define NB 512                   // buckets
#define RPB 196                  // rows per bucket (512*196 = 100352 >= N_NODES)
#define BCAP 3584                // slab capacity: mean 3136 + 8 sigma (R9-validated margin)
#define SA_EDGES 3125            // edges per scatterA WG (512*3125 = 1.6M exact)
#define CAP 16                   // LDS staging depth per bucket (R0-proven config)
#define NCH 13                   // col chunks of 8192 rows (2MB bf16 slice, fits XCD L2)
#define KEYS 2548                // NCH*RPB sort bins
#define KEYP 2560                // padded to 64*40 for single-wave scan

typedef __bf16 bf16x8 __attribute__((ext_vector_type(8)));
typedef float  f32x4  __attribute__((ext_vector_type(4)));
typedef float  f32x2  __attribute__((ext_vector_type(2)));
typedef int    i32x2  __attribute__((ext_vector_type(2)));

// ---- K1: W transpose (fp32 -> bf16 WT) + zero bucket cursors ----
__global__ __launch_bounds__(256) void prep_kernel(const float* __restrict__ W,
                                                   __bf16* __restrict__ WT,
                                                   int* __restrict__ bucketCnt) {
    int t = blockIdx.x * 256 + threadIdx.x;   // 16384 threads
    int k = t >> 7, n = t & 127;
    WT[n * D + k] = (__bf16)W[t];
    if (t < NB) bucketCnt[t] = 0;
}

// ---- K2: GEMM h = bf16(x) @ bf16(W) (verified since R6) ----
__global__ __launch_bounds__(256) void gemm_kernel(
        const float* __restrict__ x,
        const __bf16* __restrict__ WT,
        __bf16* __restrict__ h) {
    __shared__ __bf16 lsm[4][16][144];
    const int wave = threadIdx.x >> 6;
    const int lane = threadIdx.x & 63;
    const int tile = blockIdx.x * 4 + wave;
    if (tile >= N_TILES) return;
    const int m = lane & 15, quad = lane >> 4;
    const float* xp = x + (size_t)(tile * 16 + m) * D + quad * 8;

    f32x4 acc[8];
#pragma unroll
    for (int ct = 0; ct < 8; ++ct) acc[ct] = (f32x4)(0.0f);
#pragma unroll
    for (int kk = 0; kk < 4; ++kk) {
        f32x4 a0 = *(const f32x4*)(xp + kk * 32);
        f32x4 a1 = *(const f32x4*)(xp + kk * 32 + 4);
        bf16x8 a;
#pragma unroll
        for (int j = 0; j < 4; ++j) { a[j] = (__bf16)a0[j]; a[j + 4] = (__bf16)a1[j]; }
#pragma unroll
        for (int ct = 0; ct < 8; ++ct) {
            bf16x8 b = *(const bf16x8*)(WT + (size_t)(ct * 16 + m) * D + kk * 32 + quad * 8);
            acc[ct] = __builtin_amdgcn_mfma_f32_16x16x32_bf16(a, b, acc[ct], 0, 0, 0);
        }
    }
#pragma unroll
    for (int ct = 0; ct < 8; ++ct)
#pragma unroll
        for (int r = 0; r < 4; ++r)
            lsm[wave][quad * 4 + r][ct * 16 + m] = (__bf16)acc[ct][r];
#pragma unroll
    for (int i = 0; i < 4; ++i) {
        int rl = i * 4 + quad;
        bf16x8 vv = *(const bf16x8*)&lsm[wave][rl][m * 8];
        *(bf16x8*)(h + (size_t)(tile * 16 + rl) * D + m * 8) = vv;
    }
}

// ---- K3: LDS-staged scatter into fixed-capacity bucket slabs (R0-proven) ----
// pack = (localRow<<17) | col, val as bits; claims via global per-bucket cursor
__global__ __launch_bounds__(256) void scatterA_kernel(
        const int* __restrict__ rows, const int* __restrict__ cols,
        const float* __restrict__ vals,
        int* __restrict__ bucketCnt, i32x2* __restrict__ svcA) {
    __shared__ i32x2 buf[NB][CAP];   // 64 KB
    __shared__ int   cnt[NB];        // 2 KB
    for (int t = threadIdx.x; t < NB; t += 256) cnt[t] = 0;
    __syncthreads();
    const int base = blockIdx.x * SA_EDGES;
    for (int it = 0; it < 13; ++it) {
        int idx = it * 256 + threadIdx.x;
        if (idx < SA_EDGES) {
            int e = base + idx;
            int r = rows[e];
            int b = r / RPB;                  // magic-mul division by 196
            int local = r - b * RPB;
            i32x2 pk;
            pk[0] = (local << 17) | cols[e];
            pk[1] = __float_as_int(vals[e]);
            int p = atomicAdd(&cnt[b], 1);
            if (p < CAP) buf[b][p] = pk;
            else {                             // rare overflow: direct claim
                int g = atomicAdd(&bucketCnt[b], 1);
                if (g < BCAP) svcA[(size_t)b * BCAP + g] = pk;
            }
        }
    }
    __syncthreads();
    for (int t = threadIdx.x; t < NB; t += 256) {
        int n = min(cnt[t], CAP);
        if (n > 0) {
            int g = atomicAdd(&bucketCnt[t], n);
            i32x2* dst = svcA + (size_t)t * BCAP;
            for (int i = 0; i < n; ++i)
                if (g + i < BCAP) dst[g + i] = buf[t][i];   // contiguous run
        }
    }
}

// ---- K4: chunked sort (by col-chunk, then row) + segsum + relu ----
// Edges sorted by (col>>13, row): all WGs sweep the 13 chunks in the same
// order, so every CU on an XCD gathers from the same 2MB L2-resident h slice.
// Per-row accumulators live in registers across the whole chunk sweep
// (acc[13] f32x2, statically indexed — rule #20).
__device__ __forceinline__ f32x2 bf2f(unsigned u) {
    f32x2 r;
    r[0] = __int_as_float(u << 16);
    r[1] = __int_as_float(u & 0xffff0000u);
    return r;
}

__device__ __forceinline__ int sortkey(unsigned u) {
    // u = (localRow<<17) | col ; chunk = col>>13 (0..12); key = chunk*RPB + localRow
    return (int)((u >> 13) & 15u) * RPB + (int)(u >> 17);
}

__global__ __launch_bounds__(1024, 8) void sortsum_kernel(
        const __bf16* __restrict__ h, const int* __restrict__ bucketCnt,
        const i32x2* __restrict__ svcA, float* __restrict__ out) {
    __shared__ i32x2 lbuf[BCAP];     // 28672 B
    __shared__ int   lhist[KEYP];    // 10240 B
    __shared__ int   send[KEYP];     // inclusive scan (bin ends)
    __shared__ int   lcur[KEYP];     // scatter cursors (bin starts, mutated)
    const int b   = blockIdx.x;
    const int tid = threadIdx.x;
    const int n   = min(bucketCnt[b], BCAP);
    const i32x2* win = svcA + (size_t)b * BCAP;

    for (int t = tid; t < KEYP; t += 1024) lhist[t] = 0;
    __syncthreads();

    // load window into registers (<=4 recs/thread) + LDS histogram over keys
    i32x2 rec0, rec1, rec2, rec3;
    const int i0 = tid, i1 = tid + 1024, i2 = tid + 2048, i3 = tid + 3072;
    if (i0 < n) { rec0 = win[i0]; atomicAdd(&lhist[sortkey((unsigned)rec0[0])], 1); }
    if (i1 < n) { rec1 = win[i1]; atomicAdd(&lhist[sortkey((unsigned)rec1[0])], 1); }
    if (i2 < n) { rec2 = win[i2]; atomicAdd(&lhist[sortkey((unsigned)rec2[0])], 1); }
    if (i3 < n) { rec3 = win[i3]; atomicAdd(&lhist[sortkey((unsigned)rec3[0])], 1); }
    __syncthreads();

    // single-wave scan over 2560 bins: 40 contiguous bins per lane + shuffle scan
    if (tid < 64) {
        const int base = tid * 40;
        int run = 0;
#pragma unroll
        for (int j = 0; j < 40; ++j) run += lhist[base + j];
        int s = run;
#pragma unroll
        for (int d = 1; d < 64; d <<= 1) {
            int t2 = __shfl_up(s, d, 64);
            if (tid >= d) s += t2;
        }
        int acc = s - run;               // exclusive prefix of this 40-bin group
#pragma unroll
        for (int j = 0; j < 40; ++j) {
            int hv = lhist[base + j];
            lcur[base + j] = acc;
            acc += hv;
            send[base + j] = acc;
        }
    }
    __syncthreads();

    // scatter registers into (chunk,row)-sorted LDS
    if (i0 < n) { lbuf[atomicAdd(&lcur[sortkey((unsigned)rec0[0])], 1)] = rec0; }
    if (i1 < n) { lbuf[atomicAdd(&lcur[sortkey((unsigned)rec1[0])], 1)] = rec1; }
    if (i2 < n) { lbuf[atomicAdd(&lcur[sortkey((unsigned)rec2[0])], 1)] = rec2; }
    if (i3 < n) { lbuf[atomicAdd(&lcur[sortkey((unsigned)rec3[0])], 1)] = rec3; }
    __syncthreads();

    // chunk-swept segsum: outer loop = col chunk, register acc per owned row
    const int wave = tid >> 6;
    const int lane = tid & 63;
    const char* hb = (const char*)h;
    const unsigned lo4 = (unsigned)lane * 4u;

    f32x2 acc[13];
#pragma unroll
    for (int r8 = 0; r8 < 13; ++r8) acc[r8] = (f32x2)(0.0f);

    for (int c = 0; c < NCH; ++c) {
        const int kb = c * RPB;
#pragma unroll
        for (int r8 = 0; r8 < 13; ++r8) {
            const int rl = wave + (r8 << 4);
            if (rl < RPB) {
                const int k = kb + rl;
                int i = (k == 0) ? 0 : send[k - 1];
                const int e = send[k];
                f32x2 a = acc[r8];
                for (; i + 1 < e; i += 2) {
                    i32x2 q0 = lbuf[i], q1 = lbuf[i + 1];
                    unsigned u0 = *(const unsigned*)(hb + ((((unsigned)q0[0]) & 0x1FFFFu) << 8) + lo4);
                    unsigned u1 = *(const unsigned*)(hb + ((((unsigned)q1[0]) & 0x1FFFFu) << 8) + lo4);
                    a += bf2f(u0) * __int_as_float(q0[1]);
                    a += bf2f(u1) * __int_as_float(q1[1]);
                }
                if (i < e) {
                    i32x2 q0 = lbuf[i];
                    unsigned u0 = *(const unsigned*)(hb + ((((unsigned)q0[0]) & 0x1FFFFu) << 8) + lo4);
                    a += bf2f(u0) * __int_as_float(q0[1]);
                }
                acc[r8] = a;
            }
        }
    }

    // epilogue: relu + store
#pragma unroll
    for (int r8 = 0; r8 < 13; ++r8) {
        const int rl = wave + (r8 << 4);
        const int gr = b * RPB + rl;
        if (rl < RPB && gr < N_NODES) {
            f32x2 o;
            o[0] = fmaxf(acc[r8][0], 0.0f);
            o[1] = fmaxf(acc[r8][1], 0.0f);
            __builtin_nontemporal_store(o, (f32x2*)(out + (size_t)gr * D + lane * 2));
        }
    }
}

extern "C" void kernel_launch(void* const* d_in, const int* in_sizes, int n_in,
                              void* d_out, int out_size, void* d_ws, size_t ws_size,
                              hipStream_t stream) {
    const float* x    = (const float*)d_in[0];
    const float* w    = (const float*)d_in[1];
    const float* vals = (const float*)d_in[2];
    const int*   rows = (const int*)d_in[3];
    const int*   cols = (const int*)d_in[4];
    float*       out  = (float*)d_out;

    // ---- workspace (~40.3 MB) ----
    char* p = (char*)d_ws;
    __bf16* h         = (__bf16*)p;  p += (size_t)N_NODES * D * 2;          // 25.6 MB
    __bf16* WT        = (__bf16*)p;  p += (size_t)D * D * 2;                // 32 KB
    int*    bucketCnt = (int*)p;     p += 4096;                             // NB ints
    i32x2*  svcA      = (i32x2*)p;   p += (size_t)NB * BCAP * 8;            // 14.7 MB

    prep_kernel<<<64, 256, 0, stream>>>(w, WT, bucketCnt);
    gemm_kernel<<<(N_TILES + 3) / 4, 256, 0, stream>>>(x, WT, h);
    scatterA_kernel<<<NB, 256, 0, stream>>>(rows, cols, vals, bucketCnt, svcA);
    sortsum_kernel<<<NB, 1024, 0, stream>>>(h, bucketCnt, svcA, out);
}